// Round 1
// baseline (1298.788 us; speedup 1.0000x reference)
//
#include <hip/hip_runtime.h>

#define TOKENS 4096
#define DDIM   2048
#define HDIM   1024
#define NEXP   8
#define GK     2048
#define GN     2048

typedef __bf16 bf16_t;
typedef __bf16 bf16x8 __attribute__((ext_vector_type(8)));
typedef __bf16 bf16x4 __attribute__((ext_vector_type(4)));
typedef float  f32x4  __attribute__((ext_vector_type(4)));

__device__ inline void gld_lds16(const bf16_t* g, bf16_t* l) {
  __builtin_amdgcn_global_load_lds(
      (const __attribute__((address_space(1))) void*)g,
      (__attribute__((address_space(3))) void*)l, 16, 0, 0);
}

// ---------------- routing: gate_g (softmax+top2) and gate_f (softmax), fold weight[] ----------------
__global__ __launch_bounds__(256)
void k_routing(const float* __restrict__ vec,
               const float* __restrict__ Wg, const float* __restrict__ bg,
               const float* __restrict__ Wf, const float* __restrict__ bfv,
               const float* __restrict__ wgt,
               float* __restrict__ c0, float* __restrict__ c1)
{
  const int wave = threadIdx.x >> 6;
  const int lane = threadIdx.x & 63;
  const int m = blockIdx.x * 4 + wave;
  const float* v = vec + (size_t)m * DDIM;

  float ag[NEXP], af[NEXP];
#pragma unroll
  for (int e = 0; e < NEXP; ++e) { ag[e] = 0.f; af[e] = 0.f; }

  for (int i = lane; i < HDIM; i += 64) {
    const float xg = v[i];
    const float xf = v[HDIM + i];
    const float4 wg0 = *(const float4*)(Wg + i * NEXP);
    const float4 wg1 = *(const float4*)(Wg + i * NEXP + 4);
    const float4 wf0 = *(const float4*)(Wf + i * NEXP);
    const float4 wf1 = *(const float4*)(Wf + i * NEXP + 4);
    ag[0] += xg * wg0.x; ag[1] += xg * wg0.y; ag[2] += xg * wg0.z; ag[3] += xg * wg0.w;
    ag[4] += xg * wg1.x; ag[5] += xg * wg1.y; ag[6] += xg * wg1.z; ag[7] += xg * wg1.w;
    af[0] += xf * wf0.x; af[1] += xf * wf0.y; af[2] += xf * wf0.z; af[3] += xf * wf0.w;
    af[4] += xf * wf1.x; af[5] += xf * wf1.y; af[6] += xf * wf1.z; af[7] += xf * wf1.w;
  }
#pragma unroll
  for (int e = 0; e < NEXP; ++e) {
#pragma unroll
    for (int off = 32; off >= 1; off >>= 1) {
      ag[e] += __shfl_xor(ag[e], off, 64);
      af[e] += __shfl_xor(af[e], off, 64);
    }
  }
  if (lane == 0) {
    float g[NEXP], f[NEXP];
    float mg = -1e30f, mf = -1e30f;
#pragma unroll
    for (int e = 0; e < NEXP; ++e) {
      g[e] = ag[e] + bg[e]; mg = fmaxf(mg, g[e]);
      f[e] = af[e] + bfv[e]; mf = fmaxf(mf, f[e]);
    }
    float sg = 0.f, sf = 0.f;
#pragma unroll
    for (int e = 0; e < NEXP; ++e) {
      g[e] = expf(g[e] - mg); sg += g[e];
      f[e] = expf(f[e] - mf); sf += f[e];
    }
    const float rg = 1.f / sg, rf = 1.f / sf;
#pragma unroll
    for (int e = 0; e < NEXP; ++e) { g[e] *= rg; f[e] *= rf; }
    // top-2 (ties -> lower index, matching jax.lax.top_k)
    int i1 = 0;
#pragma unroll
    for (int e = 1; e < NEXP; ++e) if (g[e] > g[i1]) i1 = e;
    int i2 = (i1 == 0) ? 1 : 0;
#pragma unroll
    for (int e = 0; e < NEXP; ++e) if (e != i1 && g[e] > g[i2]) i2 = e;
    const float w0 = wgt[0], w1 = wgt[1];
#pragma unroll
    for (int e = 0; e < NEXP; ++e) {
      c0[e * TOKENS + m] = (e == i1 || e == i2) ? w0 * g[e] : 0.f;
      c1[e * TOKENS + m] = w1 * f[e];
    }
  }
}

// ---------------- fp32 -> bf16 (X) ----------------
__global__ __launch_bounds__(256)
void k_cvt(const float* __restrict__ in, bf16_t* __restrict__ out)
{
  const size_t i = ((size_t)blockIdx.x * 256 + threadIdx.x) * 8;
  const float4 a = *(const float4*)(in + i);
  const float4 b = *(const float4*)(in + i + 4);
  bf16x8 o;
  o[0] = (bf16_t)a.x; o[1] = (bf16_t)a.y; o[2] = (bf16_t)a.z; o[3] = (bf16_t)a.w;
  o[4] = (bf16_t)b.x; o[5] = (bf16_t)b.y; o[6] = (bf16_t)b.z; o[7] = (bf16_t)b.w;
  *(bf16x8*)(out + i) = o;
}

// ---------------- fp32 W[k][n] -> bf16 Wt[n][k] (per 64x64 tile via LDS) ----------------
#define TP 68
__global__ __launch_bounds__(256)
void k_cvt_wt(const float* __restrict__ W, bf16_t* __restrict__ Wt)
{
  __shared__ __attribute__((aligned(16))) bf16_t tile[64 * TP];
  const size_t eoff = (size_t)blockIdx.z * DDIM * DDIM;
  const float* w = W + eoff;
  bf16_t* wt = Wt + eoff;
  const int k0 = blockIdx.x * 64;
  const int n0 = blockIdx.y * 64;
  const int t = threadIdx.x;
  const int c4 = (t & 15) * 4;
  const int rb = (t >> 4) * 4;
#pragma unroll
  for (int rr = 0; rr < 4; ++rr) {
    const int r = rb + rr;
    const float4 v = *(const float4*)(w + (size_t)(k0 + r) * DDIM + n0 + c4);
    tile[(c4 + 0) * TP + r] = (bf16_t)v.x;
    tile[(c4 + 1) * TP + r] = (bf16_t)v.y;
    tile[(c4 + 2) * TP + r] = (bf16_t)v.z;
    tile[(c4 + 3) * TP + r] = (bf16_t)v.w;
  }
  __syncthreads();
  const int nl = t >> 2;
  const int kq = (t & 3) * 16;
  bf16_t* dst = wt + (size_t)(n0 + nl) * DDIM + k0 + kq;
#pragma unroll
  for (int j2 = 0; j2 < 4; ++j2) {
    bf16x4 u = *(const bf16x4*)(&tile[nl * TP + kq + j2 * 4]);
    *(bf16x4*)(dst + j2 * 4) = u;
  }
}

// ---------------- GEMM1: hidden = relu(X @ W1 + b1), bf16 out ----------------
// A [4096,2048] row-major bf16; Bt [2048(n),2048(k)] row-major bf16 (pre-transposed)
__global__ __launch_bounds__(256, 2)
void k_gemm_relu(const bf16_t* __restrict__ A, const bf16_t* __restrict__ Bt,
                 const float* __restrict__ bias, bf16_t* __restrict__ H)
{
  __shared__ __attribute__((aligned(16))) bf16_t As[128 * 32];
  __shared__ __attribute__((aligned(16))) bf16_t Bs[128 * 32];
  const int t = threadIdx.x;
  const int wave = t >> 6;
  const int lane = t & 63;
  const int m0 = blockIdx.x * 128;
  const int n0 = blockIdx.y * 128;
  const int wm = (wave >> 1) << 6;
  const int wn = (wave & 1) << 6;

  f32x4 acc[4][4] = {};

  const bf16_t* aP0 = A + (size_t)(m0 + (t >> 2)) * GK + (t & 3) * 8;
  const bf16_t* aP1 = aP0 + (size_t)64 * GK;
  const bf16_t* bP0 = Bt + (size_t)(n0 + (t >> 2)) * GK + (t & 3) * 8;
  const bf16_t* bP1 = bP0 + (size_t)64 * GK;
  bf16_t* lA0 = As + wave * 512;
  bf16_t* lA1 = As + 2048 + wave * 512;
  bf16_t* lB0 = Bs + wave * 512;
  bf16_t* lB1 = Bs + 2048 + wave * 512;

  const int fr = lane & 15;
  const int kq = (lane >> 4) * 8;

  for (int k0 = 0; k0 < GK; k0 += 32) {
    gld_lds16(aP0 + k0, lA0);
    gld_lds16(aP1 + k0, lA1);
    gld_lds16(bP0 + k0, lB0);
    gld_lds16(bP1 + k0, lB1);
    __syncthreads();
    bf16x8 afr[4], bfr[4];
#pragma unroll
    for (int i = 0; i < 4; ++i) {
      afr[i] = *(const bf16x8*)(As + (wm + i * 16 + fr) * 32 + kq);
      bfr[i] = *(const bf16x8*)(Bs + (wn + i * 16 + fr) * 32 + kq);
    }
#pragma unroll
    for (int i = 0; i < 4; ++i)
#pragma unroll
      for (int j = 0; j < 4; ++j)
        acc[i][j] = __builtin_amdgcn_mfma_f32_16x16x32_bf16(afr[i], bfr[j], acc[i][j], 0, 0, 0);
    __syncthreads();
  }

  const int col = lane & 15;
  const int rq  = (lane >> 4) * 4;
#pragma unroll
  for (int j = 0; j < 4; ++j) {
    const int gn = n0 + wn + j * 16 + col;
    const float bv = bias[gn];
#pragma unroll
    for (int i = 0; i < 4; ++i) {
      const int gm = m0 + wm + i * 16 + rq;
#pragma unroll
      for (int r = 0; r < 4; ++r) {
        float v = acc[i][j][r] + bv;
        v = v > 0.f ? v : 0.f;
        H[(size_t)(gm + r) * GN + gn] = (bf16_t)v;
      }
    }
  }
}

// ---------------- GEMM2: out[half] (+)= c * (hidden @ W2 + b2) ----------------
__global__ __launch_bounds__(256, 2)
void k_gemm_out(const bf16_t* __restrict__ A, const bf16_t* __restrict__ Bt,
                const float* __restrict__ bias,
                const float* __restrict__ c0, const float* __restrict__ c1,
                float* __restrict__ out0, float* __restrict__ out1, const int accum)
{
  __shared__ __attribute__((aligned(16))) bf16_t As[128 * 32];
  __shared__ __attribute__((aligned(16))) bf16_t Bs[128 * 32];
  const int t = threadIdx.x;
  const int wave = t >> 6;
  const int lane = t & 63;
  const int m0 = blockIdx.x * 128;
  const int n0 = blockIdx.y * 128;
  const int wm = (wave >> 1) << 6;
  const int wn = (wave & 1) << 6;

  f32x4 acc[4][4] = {};

  const bf16_t* aP0 = A + (size_t)(m0 + (t >> 2)) * GK + (t & 3) * 8;
  const bf16_t* aP1 = aP0 + (size_t)64 * GK;
  const bf16_t* bP0 = Bt + (size_t)(n0 + (t >> 2)) * GK + (t & 3) * 8;
  const bf16_t* bP1 = bP0 + (size_t)64 * GK;
  bf16_t* lA0 = As + wave * 512;
  bf16_t* lA1 = As + 2048 + wave * 512;
  bf16_t* lB0 = Bs + wave * 512;
  bf16_t* lB1 = Bs + 2048 + wave * 512;

  const int fr = lane & 15;
  const int kq = (lane >> 4) * 8;

  for (int k0 = 0; k0 < GK; k0 += 32) {
    gld_lds16(aP0 + k0, lA0);
    gld_lds16(aP1 + k0, lA1);
    gld_lds16(bP0 + k0, lB0);
    gld_lds16(bP1 + k0, lB1);
    __syncthreads();
    bf16x8 afr[4], bfr[4];
#pragma unroll
    for (int i = 0; i < 4; ++i) {
      afr[i] = *(const bf16x8*)(As + (wm + i * 16 + fr) * 32 + kq);
      bfr[i] = *(const bf16x8*)(Bs + (wn + i * 16 + fr) * 32 + kq);
    }
#pragma unroll
    for (int i = 0; i < 4; ++i)
#pragma unroll
      for (int j = 0; j < 4; ++j)
        acc[i][j] = __builtin_amdgcn_mfma_f32_16x16x32_bf16(afr[i], bfr[j], acc[i][j], 0, 0, 0);
    __syncthreads();
  }

  const int col = lane & 15;
  const int rq  = (lane >> 4) * 4;
#pragma unroll
  for (int j = 0; j < 4; ++j) {
    const int gn = n0 + wn + j * 16 + col;
    const float bv = bias[gn];
    const bool lo = gn < HDIM;
    float* obase = lo ? (out0 + gn) : (out1 + (gn - HDIM));
    const float* cc = lo ? c0 : c1;
#pragma unroll
    for (int i = 0; i < 4; ++i) {
      const int gmB = m0 + wm + i * 16 + rq;
#pragma unroll
      for (int r = 0; r < 4; ++r) {
        const int gm = gmB + r;
        float v = (acc[i][j][r] + bv) * cc[gm];
        float* dst = obase + (size_t)gm * HDIM;
        if (accum) v += *dst;
        *dst = v;
      }
    }
  }
}

extern "C" void kernel_launch(void* const* d_in, const int* in_sizes, int n_in,
                              void* d_out, int out_size, void* d_ws, size_t ws_size,
                              hipStream_t stream)
{
  const float* vec = (const float*)d_in[0];
  const float* Wg  = (const float*)d_in[1];
  const float* bg  = (const float*)d_in[2];
  const float* Wf  = (const float*)d_in[3];
  const float* bfv = (const float*)d_in[4];
  const float* W1  = (const float*)d_in[5];
  const float* b1  = (const float*)d_in[6];
  const float* W2  = (const float*)d_in[7];
  const float* b2  = (const float*)d_in[8];
  const float* wgt = (const float*)d_in[9];
  // d_in[10] = top_k (always 2 for this problem)

  float* out0 = (float*)d_out;
  float* out1 = out0 + (size_t)TOKENS * HDIM;

  char* base = (char*)d_ws;
  const size_t XB = (size_t)TOKENS * DDIM * 2;   // 16 MiB
  bf16_t* Xbf    = (bf16_t*)base;
  bf16_t* hidden = (bf16_t*)(base + XB);
  float*  c0     = (float*)(base + 2 * XB);
  float*  c1     = c0 + (size_t)NEXP * TOKENS;
  size_t off = 2 * XB + 2 * (size_t)NEXP * TOKENS * 4;

  k_routing<<<dim3(TOKENS / 4), 256, 0, stream>>>(vec, Wg, bg, Wf, bfv, wgt, c0, c1);
  k_cvt<<<dim3((TOKENS * DDIM) / 2048), 256, 0, stream>>>(vec, Xbf);

  const size_t WT = (size_t)NEXP * DDIM * DDIM * 2; // 64 MiB per weight tensor
  if (ws_size >= off + 2 * WT) {
    // big path: pre-convert all expert weights once
    bf16_t* W1t = (bf16_t*)(base + off);
    bf16_t* W2t = (bf16_t*)(base + off + WT);
    k_cvt_wt<<<dim3(32, 32, NEXP), 256, 0, stream>>>(W1, W1t);
    k_cvt_wt<<<dim3(32, 32, NEXP), 256, 0, stream>>>(W2, W2t);
    for (int e = 0; e < NEXP; ++e) {
      k_gemm_relu<<<dim3(32, 16), 256, 0, stream>>>(
          Xbf, W1t + (size_t)e * DDIM * DDIM, b1 + (size_t)e * DDIM, hidden);
      k_gemm_out<<<dim3(32, 16), 256, 0, stream>>>(
          hidden, W2t + (size_t)e * DDIM * DDIM, b2 + (size_t)e * DDIM,
          c0 + (size_t)e * TOKENS, c1 + (size_t)e * TOKENS, out0, out1, e > 0);
    }
  } else {
    // small-ws path: convert per-expert into reused 8 MiB buffers
    bf16_t* W1t = (bf16_t*)(base + off);
    bf16_t* W2t = W1t + (size_t)DDIM * DDIM;
    for (int e = 0; e < NEXP; ++e) {
      k_cvt_wt<<<dim3(32, 32, 1), 256, 0, stream>>>(W1 + (size_t)e * DDIM * DDIM, W1t);
      k_cvt_wt<<<dim3(32, 32, 1), 256, 0, stream>>>(W2 + (size_t)e * DDIM * DDIM, W2t);
      k_gemm_relu<<<dim3(32, 16), 256, 0, stream>>>(Xbf, W1t, b1 + (size_t)e * DDIM, hidden);
      k_gemm_out<<<dim3(32, 16), 256, 0, stream>>>(
          hidden, W2t, b2 + (size_t)e * DDIM,
          c0 + (size_t)e * TOKENS, c1 + (size_t)e * TOKENS, out0, out1, e > 0);
    }
  }
}

// Round 2
// 1071.330 us; speedup vs baseline: 1.2123x; 1.2123x over previous
//
#include <hip/hip_runtime.h>

#define TOKENS 4096
#define DDIM   2048
#define HDIM   1024
#define NEXP   8
#define GK     2048
#define GN     2048

typedef __bf16 bf16_t;
typedef __bf16 bf16x8 __attribute__((ext_vector_type(8)));
typedef __bf16 bf16x4 __attribute__((ext_vector_type(4)));
typedef float  f32x4  __attribute__((ext_vector_type(4)));

__device__ inline void gld_lds16(const bf16_t* g, bf16_t* l) {
  __builtin_amdgcn_global_load_lds(
      (const __attribute__((address_space(1))) void*)g,
      (__attribute__((address_space(3))) void*)l, 16, 0, 0);
}

// ---------------- routing: gate_g (softmax+top2) and gate_f (softmax), fold weight[] ----------------
__global__ __launch_bounds__(256)
void k_routing(const float* __restrict__ vec,
               const float* __restrict__ Wg, const float* __restrict__ bg,
               const float* __restrict__ Wf, const float* __restrict__ bfv,
               const float* __restrict__ wgt,
               float* __restrict__ c0, float* __restrict__ c1)
{
  const int wave = threadIdx.x >> 6;
  const int lane = threadIdx.x & 63;
  const int m = blockIdx.x * 4 + wave;
  const float* v = vec + (size_t)m * DDIM;

  float ag[NEXP], af[NEXP];
#pragma unroll
  for (int e = 0; e < NEXP; ++e) { ag[e] = 0.f; af[e] = 0.f; }

  for (int i = lane; i < HDIM; i += 64) {
    const float xg = v[i];
    const float xf = v[HDIM + i];
    const float4 wg0 = *(const float4*)(Wg + i * NEXP);
    const float4 wg1 = *(const float4*)(Wg + i * NEXP + 4);
    const float4 wf0 = *(const float4*)(Wf + i * NEXP);
    const float4 wf1 = *(const float4*)(Wf + i * NEXP + 4);
    ag[0] += xg * wg0.x; ag[1] += xg * wg0.y; ag[2] += xg * wg0.z; ag[3] += xg * wg0.w;
    ag[4] += xg * wg1.x; ag[5] += xg * wg1.y; ag[6] += xg * wg1.z; ag[7] += xg * wg1.w;
    af[0] += xf * wf0.x; af[1] += xf * wf0.y; af[2] += xf * wf0.z; af[3] += xf * wf0.w;
    af[4] += xf * wf1.x; af[5] += xf * wf1.y; af[6] += xf * wf1.z; af[7] += xf * wf1.w;
  }
#pragma unroll
  for (int e = 0; e < NEXP; ++e) {
#pragma unroll
    for (int off = 32; off >= 1; off >>= 1) {
      ag[e] += __shfl_xor(ag[e], off, 64);
      af[e] += __shfl_xor(af[e], off, 64);
    }
  }
  if (lane == 0) {
    float g[NEXP], f[NEXP];
    float mg = -1e30f, mf = -1e30f;
#pragma unroll
    for (int e = 0; e < NEXP; ++e) {
      g[e] = ag[e] + bg[e]; mg = fmaxf(mg, g[e]);
      f[e] = af[e] + bfv[e]; mf = fmaxf(mf, f[e]);
    }
    float sg = 0.f, sf = 0.f;
#pragma unroll
    for (int e = 0; e < NEXP; ++e) {
      g[e] = expf(g[e] - mg); sg += g[e];
      f[e] = expf(f[e] - mf); sf += f[e];
    }
    const float rg = 1.f / sg, rf = 1.f / sf;
#pragma unroll
    for (int e = 0; e < NEXP; ++e) { g[e] *= rg; f[e] *= rf; }
    int i1 = 0;
#pragma unroll
    for (int e = 1; e < NEXP; ++e) if (g[e] > g[i1]) i1 = e;
    int i2 = (i1 == 0) ? 1 : 0;
#pragma unroll
    for (int e = 0; e < NEXP; ++e) if (e != i1 && g[e] > g[i2]) i2 = e;
    const float w0 = wgt[0], w1 = wgt[1];
#pragma unroll
    for (int e = 0; e < NEXP; ++e) {
      c0[e * TOKENS + m] = (e == i1 || e == i2) ? w0 * g[e] : 0.f;
      c1[e * TOKENS + m] = w1 * f[e];
    }
  }
}

// ---------------- fp32 -> bf16 (X) ----------------
__global__ __launch_bounds__(256)
void k_cvt(const float* __restrict__ in, bf16_t* __restrict__ out)
{
  const size_t i = ((size_t)blockIdx.x * 256 + threadIdx.x) * 8;
  const float4 a = *(const float4*)(in + i);
  const float4 b = *(const float4*)(in + i + 4);
  bf16x8 o;
  o[0] = (bf16_t)a.x; o[1] = (bf16_t)a.y; o[2] = (bf16_t)a.z; o[3] = (bf16_t)a.w;
  o[4] = (bf16_t)b.x; o[5] = (bf16_t)b.y; o[6] = (bf16_t)b.z; o[7] = (bf16_t)b.w;
  *(bf16x8*)(out + i) = o;
}

// ---------------- fp32 W[k][n] -> bf16 Wt[n][k] (64x64 tile via LDS) ----------------
#define TP 68
__global__ __launch_bounds__(256)
void k_cvt_wt(const float* __restrict__ W, bf16_t* __restrict__ Wt)
{
  __shared__ __attribute__((aligned(16))) bf16_t tile[64 * TP];
  const size_t eoff = (size_t)blockIdx.z * DDIM * DDIM;
  const float* w = W + eoff;
  bf16_t* wt = Wt + eoff;
  const int k0 = blockIdx.x * 64;
  const int n0 = blockIdx.y * 64;
  const int t = threadIdx.x;
  const int c4 = (t & 15) * 4;
  const int rb = (t >> 4) * 4;
#pragma unroll
  for (int rr = 0; rr < 4; ++rr) {
    const int r = rb + rr;
    const float4 v = *(const float4*)(w + (size_t)(k0 + r) * DDIM + n0 + c4);
    tile[(c4 + 0) * TP + r] = (bf16_t)v.x;
    tile[(c4 + 1) * TP + r] = (bf16_t)v.y;
    tile[(c4 + 2) * TP + r] = (bf16_t)v.z;
    tile[(c4 + 3) * TP + r] = (bf16_t)v.w;
  }
  __syncthreads();
  const int nl = t >> 2;
  const int kq = (t & 3) * 16;
  bf16_t* dst = wt + (size_t)(n0 + nl) * DDIM + k0 + kq;
#pragma unroll
  for (int j2 = 0; j2 < 4; ++j2) {
    bf16x4 u = *(const bf16x4*)(&tile[nl * TP + kq + j2 * 4]);
    *(bf16x4*)(dst + j2 * 4) = u;
  }
}

// ---------------- GEMM1 (all experts): hidden_e = relu(X @ W1_e + b1_e), bf16 ----------------
// grid (32, 16, E). A [4096,2048] bf16; W1t [E][n][k] bf16; hidden [E][4096][2048] bf16.
__global__ __launch_bounds__(256, 2)
void k_gemm_relu(const bf16_t* __restrict__ A, const bf16_t* __restrict__ W1t,
                 const float* __restrict__ b1, bf16_t* __restrict__ Hd)
{
  __shared__ __attribute__((aligned(16))) bf16_t As[128 * 32];
  __shared__ __attribute__((aligned(16))) bf16_t Bs[128 * 32];
  const int e = blockIdx.z;
  const bf16_t* Bt = W1t + (size_t)e * GK * GN;
  const float* bias = b1 + (size_t)e * GN;
  bf16_t* H = Hd + (size_t)e * TOKENS * GN;

  const int t = threadIdx.x;
  const int wave = t >> 6;
  const int lane = t & 63;
  const int m0 = blockIdx.x * 128;
  const int n0 = blockIdx.y * 128;
  const int wm = (wave >> 1) << 6;
  const int wn = (wave & 1) << 6;

  f32x4 acc[4][4] = {};

  const bf16_t* aP0 = A + (size_t)(m0 + (t >> 2)) * GK + (t & 3) * 8;
  const bf16_t* aP1 = aP0 + (size_t)64 * GK;
  const bf16_t* bP0 = Bt + (size_t)(n0 + (t >> 2)) * GK + (t & 3) * 8;
  const bf16_t* bP1 = bP0 + (size_t)64 * GK;
  bf16_t* lA0 = As + wave * 512;
  bf16_t* lA1 = As + 2048 + wave * 512;
  bf16_t* lB0 = Bs + wave * 512;
  bf16_t* lB1 = Bs + 2048 + wave * 512;

  const int fr = lane & 15;
  const int kq = (lane >> 4) * 8;

  for (int k0 = 0; k0 < GK; k0 += 32) {
    gld_lds16(aP0 + k0, lA0);
    gld_lds16(aP1 + k0, lA1);
    gld_lds16(bP0 + k0, lB0);
    gld_lds16(bP1 + k0, lB1);
    __syncthreads();
    bf16x8 afr[4], bfr[4];
#pragma unroll
    for (int i = 0; i < 4; ++i) {
      afr[i] = *(const bf16x8*)(As + (wm + i * 16 + fr) * 32 + kq);
      bfr[i] = *(const bf16x8*)(Bs + (wn + i * 16 + fr) * 32 + kq);
    }
#pragma unroll
    for (int i = 0; i < 4; ++i)
#pragma unroll
      for (int j = 0; j < 4; ++j)
        acc[i][j] = __builtin_amdgcn_mfma_f32_16x16x32_bf16(afr[i], bfr[j], acc[i][j], 0, 0, 0);
    __syncthreads();
  }

  const int col = lane & 15;
  const int rq  = (lane >> 4) * 4;
#pragma unroll
  for (int j = 0; j < 4; ++j) {
    const int gn = n0 + wn + j * 16 + col;
    const float bv = bias[gn];
#pragma unroll
    for (int i = 0; i < 4; ++i) {
      const int gm = m0 + wm + i * 16 + rq;
#pragma unroll
      for (int r = 0; r < 4; ++r) {
        float v = acc[i][j][r] + bv;
        v = v > 0.f ? v : 0.f;
        H[(size_t)(gm + r) * GN + gn] = (bf16_t)v;
      }
    }
  }
}

// ---------------- GEMM2 (expert-summed): out = sum_e c_e[m] * (hidden_e @ W2_e + b2_e) ----------------
// grid (32, 16). Output written exactly once.
__global__ __launch_bounds__(256, 2)
void k_gemm2_sum(const bf16_t* __restrict__ Hd, const bf16_t* __restrict__ W2t,
                 const float* __restrict__ b2,
                 const float* __restrict__ c0, const float* __restrict__ c1,
                 float* __restrict__ out0, float* __restrict__ out1)
{
  __shared__ __attribute__((aligned(16))) bf16_t As[128 * 32];
  __shared__ __attribute__((aligned(16))) bf16_t Bs[128 * 32];
  __shared__ float cs[NEXP][128];   // combine coeff for this block's 128 rows, per expert
  __shared__ float bs[NEXP][128];   // bias for this block's 128 cols, per expert

  const int t = threadIdx.x;
  const int wave = t >> 6;
  const int lane = t & 63;
  const int m0 = blockIdx.x * 128;
  const int n0 = blockIdx.y * 128;
  const int wm = (wave >> 1) << 6;
  const int wn = (wave & 1) << 6;

  const bool hi = (n0 >= HDIM);
  const float* cc = hi ? c1 : c0;

  // stage c and bias (1024 floats each, 256 threads -> 4 apiece)
#pragma unroll
  for (int idx = t; idx < NEXP * 128; idx += 256) {
    const int e = idx >> 7, r = idx & 127;
    cs[e][r] = cc[e * TOKENS + m0 + r];
    bs[e][r] = b2[e * DDIM + n0 + r];
  }
  // (first K-iter __syncthreads covers visibility before epilogue-side reads)

  f32x4 fin[4][4] = {};

  const int fr = lane & 15;
  const int kq = (lane >> 4) * 8;
  const int rowOff = (t >> 2);
  const int kOff = (t & 3) * 8;
  bf16_t* lA0 = As + wave * 512;
  bf16_t* lA1 = As + 2048 + wave * 512;
  bf16_t* lB0 = Bs + wave * 512;
  bf16_t* lB1 = Bs + 2048 + wave * 512;

  for (int e = 0; e < NEXP; ++e) {
    const bf16_t* aP0 = Hd + (size_t)e * TOKENS * GK + (size_t)(m0 + rowOff) * GK + kOff;
    const bf16_t* aP1 = aP0 + (size_t)64 * GK;
    const bf16_t* bP0 = W2t + (size_t)e * GN * GK + (size_t)(n0 + rowOff) * GK + kOff;
    const bf16_t* bP1 = bP0 + (size_t)64 * GK;

    f32x4 acc[4][4] = {};
    for (int k0 = 0; k0 < GK; k0 += 32) {
      gld_lds16(aP0 + k0, lA0);
      gld_lds16(aP1 + k0, lA1);
      gld_lds16(bP0 + k0, lB0);
      gld_lds16(bP1 + k0, lB1);
      __syncthreads();
      bf16x8 afr[4], bfr[4];
#pragma unroll
      for (int i = 0; i < 4; ++i) {
        afr[i] = *(const bf16x8*)(As + (wm + i * 16 + fr) * 32 + kq);
        bfr[i] = *(const bf16x8*)(Bs + (wn + i * 16 + fr) * 32 + kq);
      }
#pragma unroll
      for (int i = 0; i < 4; ++i)
#pragma unroll
        for (int j = 0; j < 4; ++j)
          acc[i][j] = __builtin_amdgcn_mfma_f32_16x16x32_bf16(afr[i], bfr[j], acc[i][j], 0, 0, 0);
      __syncthreads();
    }

    // fold this expert: fin += c_e[row] * (acc + b2_e[col])
    const int colL = wn + (lane & 15);
    const int rqL  = wm + (lane >> 4) * 4;
#pragma unroll
    for (int j = 0; j < 4; ++j) {
      const float bv = bs[e][colL + j * 16];
#pragma unroll
      for (int i = 0; i < 4; ++i) {
#pragma unroll
        for (int r = 0; r < 4; ++r) {
          const float ce = cs[e][rqL + i * 16 + r];
          fin[i][j][r] += ce * (acc[i][j][r] + bv);
        }
      }
    }
  }

  const int col = lane & 15;
  const int rq  = (lane >> 4) * 4;
#pragma unroll
  for (int j = 0; j < 4; ++j) {
    const int gn = n0 + wn + j * 16 + col;
    float* obase = hi ? (out1 + (gn - HDIM)) : (out0 + gn);
#pragma unroll
    for (int i = 0; i < 4; ++i) {
      const int gm = m0 + wm + i * 16 + rq;
#pragma unroll
      for (int r = 0; r < 4; ++r)
        obase[(size_t)(gm + r) * HDIM] = fin[i][j][r];
    }
  }
}

// ---------------- legacy per-expert GEMM2 (small-ws fallback) ----------------
__global__ __launch_bounds__(256, 2)
void k_gemm_out(const bf16_t* __restrict__ A, const bf16_t* __restrict__ Bt,
                const float* __restrict__ bias,
                const float* __restrict__ c0, const float* __restrict__ c1,
                float* __restrict__ out0, float* __restrict__ out1, const int accum)
{
  __shared__ __attribute__((aligned(16))) bf16_t As[128 * 32];
  __shared__ __attribute__((aligned(16))) bf16_t Bs[128 * 32];
  const int t = threadIdx.x;
  const int wave = t >> 6;
  const int lane = t & 63;
  const int m0 = blockIdx.x * 128;
  const int n0 = blockIdx.y * 128;
  const int wm = (wave >> 1) << 6;
  const int wn = (wave & 1) << 6;

  f32x4 acc[4][4] = {};

  const bf16_t* aP0 = A + (size_t)(m0 + (t >> 2)) * GK + (t & 3) * 8;
  const bf16_t* aP1 = aP0 + (size_t)64 * GK;
  const bf16_t* bP0 = Bt + (size_t)(n0 + (t >> 2)) * GK + (t & 3) * 8;
  const bf16_t* bP1 = bP0 + (size_t)64 * GK;
  bf16_t* lA0 = As + wave * 512;
  bf16_t* lA1 = As + 2048 + wave * 512;
  bf16_t* lB0 = Bs + wave * 512;
  bf16_t* lB1 = Bs + 2048 + wave * 512;

  const int fr = lane & 15;
  const int kq = (lane >> 4) * 8;

  for (int k0 = 0; k0 < GK; k0 += 32) {
    gld_lds16(aP0 + k0, lA0);
    gld_lds16(aP1 + k0, lA1);
    gld_lds16(bP0 + k0, lB0);
    gld_lds16(bP1 + k0, lB1);
    __syncthreads();
    bf16x8 afr[4], bfr[4];
#pragma unroll
    for (int i = 0; i < 4; ++i) {
      afr[i] = *(const bf16x8*)(As + (wm + i * 16 + fr) * 32 + kq);
      bfr[i] = *(const bf16x8*)(Bs + (wn + i * 16 + fr) * 32 + kq);
    }
#pragma unroll
    for (int i = 0; i < 4; ++i)
#pragma unroll
      for (int j = 0; j < 4; ++j)
        acc[i][j] = __builtin_amdgcn_mfma_f32_16x16x32_bf16(afr[i], bfr[j], acc[i][j], 0, 0, 0);
    __syncthreads();
  }

  const int col = lane & 15;
  const int rq  = (lane >> 4) * 4;
#pragma unroll
  for (int j = 0; j < 4; ++j) {
    const int gn = n0 + wn + j * 16 + col;
    const float bv = bias[gn];
    const bool lo = gn < HDIM;
    float* obase = lo ? (out0 + gn) : (out1 + (gn - HDIM));
    const float* cc = lo ? c0 : c1;
#pragma unroll
    for (int i = 0; i < 4; ++i) {
      const int gmB = m0 + wm + i * 16 + rq;
#pragma unroll
      for (int r = 0; r < 4; ++r) {
        const int gm = gmB + r;
        float v = (acc[i][j][r] + bv) * cc[gm];
        float* dst = obase + (size_t)gm * HDIM;
        if (accum) v += *dst;
        *dst = v;
      }
    }
  }
}

extern "C" void kernel_launch(void* const* d_in, const int* in_sizes, int n_in,
                              void* d_out, int out_size, void* d_ws, size_t ws_size,
                              hipStream_t stream)
{
  const float* vec = (const float*)d_in[0];
  const float* Wg  = (const float*)d_in[1];
  const float* bg  = (const float*)d_in[2];
  const float* Wf  = (const float*)d_in[3];
  const float* bfv = (const float*)d_in[4];
  const float* W1  = (const float*)d_in[5];
  const float* b1  = (const float*)d_in[6];
  const float* W2  = (const float*)d_in[7];
  const float* b2  = (const float*)d_in[8];
  const float* wgt = (const float*)d_in[9];

  float* out0 = (float*)d_out;
  float* out1 = out0 + (size_t)TOKENS * HDIM;

  char* base = (char*)d_ws;
  const size_t XB = (size_t)TOKENS * DDIM * 2;        // 16 MiB
  const size_t HB = (size_t)NEXP * TOKENS * DDIM * 2; // 128 MiB
  const size_t WT = (size_t)NEXP * DDIM * DDIM * 2;   // 64 MiB each

  bf16_t* Xbf = (bf16_t*)base;
  float*  c0  = (float*)(base + XB);
  float*  c1  = c0 + (size_t)NEXP * TOKENS;
  size_t off = XB + 2 * (size_t)NEXP * TOKENS * 4;

  k_routing<<<dim3(TOKENS / 4), 256, 0, stream>>>(vec, Wg, bg, Wf, bfv, wgt, c0, c1);
  k_cvt<<<dim3((TOKENS * DDIM) / 2048), 256, 0, stream>>>(vec, Xbf);

  if (ws_size >= off + HB + 2 * WT) {
    // big path: per-expert hidden + both weight tensors pre-converted
    bf16_t* hidden = (bf16_t*)(base + off);
    bf16_t* W1t    = (bf16_t*)(base + off + HB);
    bf16_t* W2t    = (bf16_t*)(base + off + HB + WT);
    k_cvt_wt<<<dim3(32, 32, NEXP), 256, 0, stream>>>(W1, W1t);
    k_cvt_wt<<<dim3(32, 32, NEXP), 256, 0, stream>>>(W2, W2t);
    k_gemm_relu<<<dim3(32, 16, NEXP), 256, 0, stream>>>(Xbf, W1t, b1, hidden);
    k_gemm2_sum<<<dim3(32, 16), 256, 0, stream>>>(hidden, W2t, b2, c0, c1, out0, out1);
  } else {
    // small-ws fallback: sequential per-expert with reused buffers
    bf16_t* hidden = (bf16_t*)(base + off);
    bf16_t* W1t    = hidden + (size_t)TOKENS * DDIM;
    bf16_t* W2t    = W1t + (size_t)DDIM * DDIM;
    for (int e = 0; e < NEXP; ++e) {
      k_cvt_wt<<<dim3(32, 32, 1), 256, 0, stream>>>(W1 + (size_t)e * DDIM * DDIM, W1t);
      k_cvt_wt<<<dim3(32, 32, 1), 256, 0, stream>>>(W2 + (size_t)e * DDIM * DDIM, W2t);
      k_gemm_relu<<<dim3(32, 16, 1), 256, 0, stream>>>(Xbf, W1t, b1 + (size_t)e * DDIM, hidden);
      k_gemm_out<<<dim3(32, 16), 256, 0, stream>>>(
          hidden, W2t, b2 + (size_t)e * DDIM,
          c0 + (size_t)e * TOKENS, c1 + (size_t)e * TOKENS, out0, out1, e > 0);
    }
  }
}